// Round 1
// baseline (149.006 us; speedup 1.0000x reference)
//
#include <hip/hip_runtime.h>

typedef __bf16 bf16x8 __attribute__((ext_vector_type(8)));
typedef float f32x4 __attribute__((ext_vector_type(4)));
typedef unsigned int uint4v __attribute__((ext_vector_type(4)));
typedef unsigned short ushort_t;
typedef unsigned int uint_t;

#define RS 0.08838834764831845f   // 1/sqrt(128)
#define XPITCH 136                 // bf16 elems per x row in LDS (128 + 8 pad, keeps 16B align, rotates banks)
#define APITCH 72                  // bf16 elems per attn row in LDS

__device__ __forceinline__ ushort_t f2bf(float f) {
    uint_t u = __float_as_uint(f);
    u += 0x7FFFu + ((u >> 16) & 1u);   // round-to-nearest-even
    return (ushort_t)(u >> 16);
}
__device__ __forceinline__ float bf2f(ushort_t s) {
    return __uint_as_float(((uint_t)s) << 16);
}
union U4B8 { uint4v u; bf16x8 b; };
__device__ __forceinline__ bf16x8 as_bf16x8(uint4v u) { U4B8 x; x.u = u; return x.b; }

// ---------------------------------------------------------------------------
// K1a: per-slot prep.  K'[m,d] = sum_e keys[m,e]*Wq[e,d]; c[m] = bq . keys[m];
// ops[m] cast to bf16 and swizzled into MFMA B-fragment order:
//   frag(m, ks, dt), lane L holds ops[m][d = dt*16 + (L&15)][e = ks*32 + (L>>4)*8 + j], j=0..7
// ---------------------------------------------------------------------------
__global__ __launch_bounds__(256) void prep_kernel(
    const float* __restrict__ keys, const float* __restrict__ ops,
    const float* __restrict__ Wq, const float* __restrict__ bq,
    float* __restrict__ Kp, float* __restrict__ cb, ushort_t* __restrict__ ops_sw)
{
    const int m = blockIdx.x;
    const int tid = threadIdx.x;

    const float* om = ops + (size_t)m * 16384;
    for (int i = tid; i < 16384; i += 256) {          // coalesced read of ops[m]
        int d = i >> 7, e = i & 127;
        int ks = e >> 5, dt = d >> 4;
        int lane = ((e >> 3) & 3) * 16 + (d & 15);
        int j = e & 7;
        ops_sw[((((m * 4 + ks) * 8 + dt) * 64 + lane) << 3) | j] = f2bf(om[i]);
    }

    if (tid < 128) {
        int d = tid;
        float acc = 0.f;
        for (int e = 0; e < 128; ++e)
            acc = fmaf(keys[m * 128 + e], Wq[e * 128 + d], acc);
        Kp[m * 128 + d] = acc;
    } else if (tid == 128) {
        float acc = 0.f;
        for (int e = 0; e < 128; ++e)
            acc = fmaf(bq[e], keys[m * 128 + e], acc);
        cb[m] = acc;
    }
}

// ---------------------------------------------------------------------------
// K1b: swizzle K' into B-frag order for the logits GEMM:
//   frag(ki, mt), lane L holds K'[m = mt*16 + (L&15)][d = ki*32 + (L>>4)*8 + j]
// ---------------------------------------------------------------------------
__global__ __launch_bounds__(256) void swz_kp_kernel(
    const float* __restrict__ Kp, ushort_t* __restrict__ kp_sw)
{
    int i = blockIdx.x * 256 + threadIdx.x;   // grid 32 -> 8192 elems
    int j = i & 7, lane = (i >> 3) & 63, mt = (i >> 9) & 3, ki = i >> 11;
    int mm = mt * 16 + (lane & 15);
    int d = ki * 32 + (lane >> 4) * 8 + j;
    kp_sw[i] = f2bf(Kp[mm * 128 + d]);
}

// ---------------------------------------------------------------------------
// K3: main fused kernel. Block = 64 tokens x (half of the 64 slots, kb).
// Phase 1: stage x tile bf16 in LDS (single staging, stationary all K).
// Phase 2: logits via MFMA (xs @ K'^T) + softmax -> attn bf16 in LDS.
// Phase 3: per slot m: S = x_tile @ ops_bf16[m] (MFMA, B-frags straight from
//          global in frag order), then C += attn[t,m] * S in fp32 registers.
// Epilogue: atomicAdd C into zeroed d_out (K-split=2 partial sums).
// Only TWO __syncthreads in the whole kernel; no per-K-iter barrier.
// ---------------------------------------------------------------------------
__global__ __launch_bounds__(256, 2) void main_kernel(
    const float* __restrict__ x, const float* __restrict__ cb,
    const ushort_t* __restrict__ kp_sw, const ushort_t* __restrict__ ops_sw,
    float* __restrict__ out)
{
    __shared__ ushort_t xs[64 * XPITCH];
    __shared__ ushort_t attn_s[64 * APITCH];

    const int tid = threadIdx.x;
    const int lane = tid & 63;
    const int w = tid >> 6;
    const int q = lane >> 4;
    const int l15 = lane & 15;
    const int tb = blockIdx.x >> 1;
    const int kb = blockIdx.x & 1;
    const int t0 = tb * 64;

    // ---- Phase 1: stage x tile (64 x 128) as bf16, coalesced float4 reads
    const float4* x4 = (const float4*)(x + (size_t)t0 * 128);
    for (int i = tid; i < 64 * 32; i += 256) {
        int row = i >> 5, c4 = i & 31;
        float4 v = x4[row * 32 + c4];
        ushort4 s;
        s.x = f2bf(v.x); s.y = f2bf(v.y); s.z = f2bf(v.z); s.w = f2bf(v.w);
        *(ushort4*)&xs[row * XPITCH + c4 * 4] = s;
    }
    __syncthreads();

    // ---- Phase 2: attn for this tile's 64 tokens (wave w owns tokens w*16..w*16+15)
    {
        f32x4 L0 = {0.f,0.f,0.f,0.f}, L1 = {0.f,0.f,0.f,0.f},
              L2 = {0.f,0.f,0.f,0.f}, L3 = {0.f,0.f,0.f,0.f};
        const uint4v* kpf = (const uint4v*)kp_sw;
        #pragma unroll
        for (int ki = 0; ki < 4; ++ki) {
            bf16x8 a = *(const bf16x8*)&xs[(w * 16 + l15) * XPITCH + ki * 32 + q * 8];
            L0 = __builtin_amdgcn_mfma_f32_16x16x32_bf16(a, as_bf16x8(kpf[(ki*4+0)*64 + lane]), L0, 0,0,0);
            L1 = __builtin_amdgcn_mfma_f32_16x16x32_bf16(a, as_bf16x8(kpf[(ki*4+1)*64 + lane]), L1, 0,0,0);
            L2 = __builtin_amdgcn_mfma_f32_16x16x32_bf16(a, as_bf16x8(kpf[(ki*4+2)*64 + lane]), L2, 0,0,0);
            L3 = __builtin_amdgcn_mfma_f32_16x16x32_bf16(a, as_bf16x8(kpf[(ki*4+3)*64 + lane]), L3, 0,0,0);
        }
        float c0 = cb[l15], c1 = cb[16 + l15], c2 = cb[32 + l15], c3 = cb[48 + l15];
        #pragma unroll
        for (int r = 0; r < 4; ++r) {
            float v0 = (L0[r] + c0) * RS;
            float v1 = (L1[r] + c1) * RS;
            float v2 = (L2[r] + c2) * RS;
            float v3 = (L3[r] + c3) * RS;
            float mx = fmaxf(fmaxf(v0, v1), fmaxf(v2, v3));
            #pragma unroll
            for (int off = 1; off < 16; off <<= 1) mx = fmaxf(mx, __shfl_xor(mx, off));
            float e0 = __expf(v0 - mx), e1 = __expf(v1 - mx),
                  e2 = __expf(v2 - mx), e3 = __expf(v3 - mx);
            float sm = e0 + e1 + e2 + e3;
            #pragma unroll
            for (int off = 1; off < 16; off <<= 1) sm += __shfl_xor(sm, off);
            float inv = 1.0f / sm;
            int t = w * 16 + q * 4 + r;
            attn_s[t * APITCH +      l15] = f2bf(e0 * inv);
            attn_s[t * APITCH + 16 + l15] = f2bf(e1 * inv);
            attn_s[t * APITCH + 32 + l15] = f2bf(e2 * inv);
            attn_s[t * APITCH + 48 + l15] = f2bf(e3 * inv);
        }
    }
    __syncthreads();

    // ---- Phase 3: main GEMM over this block's 32 slots
    const int wy = w >> 1, wx = w & 1;            // wave region: 32 tokens x 64 d
    const int arow0 = (wy * 32 +      l15) * XPITCH + q * 8;
    const int arow1 = (wy * 32 + 16 + l15) * XPITCH + q * 8;
    const uint4v* ob = (const uint4v*)ops_sw
                     + ((size_t)(kb * 32) * 32 + (size_t)wx * 4) * 64 + lane;

    f32x4 C[2][4] = {};
    for (int ml = 0; ml < 32; ++ml) {
        f32x4 S[2][4] = {};
        const uint4v* bp = ob + (size_t)ml * 2048;  // 4ki * 8dt * 64 lanes per slot
        #pragma unroll
        for (int ki = 0; ki < 4; ++ki) {
            bf16x8 a0 = *(const bf16x8*)&xs[arow0 + ki * 32];
            bf16x8 a1 = *(const bf16x8*)&xs[arow1 + ki * 32];
            #pragma unroll
            for (int df = 0; df < 4; ++df) {
                bf16x8 b = as_bf16x8(bp[(ki * 8 + df) * 64]);
                S[0][df] = __builtin_amdgcn_mfma_f32_16x16x32_bf16(a0, b, S[0][df], 0,0,0);
                S[1][df] = __builtin_amdgcn_mfma_f32_16x16x32_bf16(a1, b, S[1][df], 0,0,0);
            }
        }
        const int m = kb * 32 + ml;
        #pragma unroll
        for (int tf = 0; tf < 2; ++tf) {
            float aw[4];
            #pragma unroll
            for (int r = 0; r < 4; ++r)            // broadcast reads within quad
                aw[r] = bf2f(attn_s[(wy * 32 + tf * 16 + q * 4 + r) * APITCH + m]);
            #pragma unroll
            for (int df = 0; df < 4; ++df)
                #pragma unroll
                for (int r = 0; r < 4; ++r)
                    C[tf][df][r] = fmaf(aw[r], S[tf][df][r], C[tf][df][r]);
        }
    }

    // ---- Epilogue
    #pragma unroll
    for (int tf = 0; tf < 2; ++tf)
        #pragma unroll
        for (int df = 0; df < 4; ++df)
            #pragma unroll
            for (int r = 0; r < 4; ++r) {
                int t = t0 + wy * 32 + tf * 16 + q * 4 + r;
                int d = wx * 64 + df * 16 + l15;
                atomicAdd(&out[(size_t)t * 128 + d], C[tf][df][r]);
            }
}

// ---------------------------------------------------------------------------
extern "C" void kernel_launch(void* const* d_in, const int* in_sizes, int n_in,
                              void* d_out, int out_size, void* d_ws, size_t ws_size,
                              hipStream_t stream)
{
    const float* x    = (const float*)d_in[0];   // (4,4096,128)
    const float* keys = (const float*)d_in[1];   // (64,128)
    const float* ops  = (const float*)d_in[2];   // (64,128,128)
    const float* Wq   = (const float*)d_in[3];   // (128,128)
    const float* bq   = (const float*)d_in[4];   // (128,)
    float* out = (float*)d_out;

    char* ws = (char*)d_ws;
    float*    Kp     = (float*)ws;               // 32 KB
    float*    cb     = (float*)(ws + 32768);     // 256 B
    ushort_t* kp_sw  = (ushort_t*)(ws + 33280);  // 16 KB
    ushort_t* ops_sw = (ushort_t*)(ws + 65536);  // 2 MB

    hipMemsetAsync(d_out, 0, (size_t)out_size * sizeof(float), stream);
    prep_kernel<<<64, 256, 0, stream>>>(keys, ops, Wq, bq, Kp, cb, ops_sw);
    swz_kp_kernel<<<32, 256, 0, stream>>>(Kp, kp_sw);
    main_kernel<<<512, 256, 0, stream>>>(x, cb, kp_sw, ops_sw, out);
}

// Round 2
// 134.906 us; speedup vs baseline: 1.1045x; 1.1045x over previous
//
#include <hip/hip_runtime.h>

typedef __bf16 bf16x8 __attribute__((ext_vector_type(8)));
typedef float f32x4 __attribute__((ext_vector_type(4)));
typedef unsigned int uint4v __attribute__((ext_vector_type(4)));
typedef unsigned short ushort_t;
typedef unsigned int uint_t;

#define RS 0.08838834764831845f   // 1/sqrt(128)
#define AP 68                      // attn_f pitch (floats)

__device__ __forceinline__ ushort_t f2bf(float f) {
    uint_t u = __float_as_uint(f);
    u += 0x7FFFu + ((u >> 16) & 1u);   // round-to-nearest-even
    return (ushort_t)(u >> 16);
}
__device__ __forceinline__ uint_t pack2(float a, float b) {
    return (uint_t)f2bf(a) | ((uint_t)f2bf(b) << 16);
}
union U4B8 { uint4v u; bf16x8 b; };
__device__ __forceinline__ bf16x8 as_bf(uint4v u) { U4B8 x; x.u = u; return x.b; }

// ---------------------------------------------------------------------------
// P1: ops -> ops_sw in MFMA B-frag order. One thread per 8-elem frag octet:
// two coalesced float4 reads, one coalesced 16B write. (R0's prep did 1M
// scattered 2B stores -> ~80us; this is read 4MB + write 2MB coalesced.)
// frag(m,ks,dt): lane L holds ops[m][d=dt*16+(L&15)][e=ks*32+(L>>4)*8+j]
// ---------------------------------------------------------------------------
__global__ __launch_bounds__(256) void p1_kernel(
    const float* __restrict__ ops, uint4v* __restrict__ ops_sw)
{
    int g = blockIdx.x * 256 + threadIdx.x;     // [0, 131072)
    int L = g & 63, dt = (g >> 6) & 7, ks = (g >> 9) & 3, m = g >> 11;
    int d = dt * 16 + (L & 15);
    int e0 = ks * 32 + ((L >> 4) << 3);
    const float4* s = (const float4*)(ops + (((size_t)(m * 128 + d)) << 7) + e0);
    float4 v0 = s[0], v1 = s[1];
    uint4v o = { pack2(v0.x, v0.y), pack2(v0.z, v0.w),
                 pack2(v1.x, v1.y), pack2(v1.z, v1.w) };
    ops_sw[g] = o;
}

// ---------------------------------------------------------------------------
// K0: K'[m] = keys[m] @ Wq (written straight into B-frag order) ; cb[m]=bq.keys[m]
// ---------------------------------------------------------------------------
__global__ __launch_bounds__(192) void k0_kernel(
    const float* __restrict__ keys, const float* __restrict__ Wq,
    const float* __restrict__ bq, ushort_t* __restrict__ kp_sw,
    float* __restrict__ cb)
{
    int m = blockIdx.x, tid = threadIdx.x;
    if (tid < 128) {
        float acc = 0.f;
        for (int e = 0; e < 128; ++e)
            acc = fmaf(keys[m * 128 + e], Wq[e * 128 + tid], acc);
        int ki = tid >> 5, q = (tid >> 3) & 3, j = tid & 7;
        int mt = m >> 4, l15 = m & 15;
        kp_sw[((((ki * 4 + mt) * 64) + (q * 16 + l15)) << 3) | j] = f2bf(acc);
    } else if (tid == 128) {
        float acc = 0.f;
        for (int e = 0; e < 128; ++e)
            acc = fmaf(bq[e], keys[m * 128 + e], acc);
        cb[m] = acc;
    }
}

// ---------------------------------------------------------------------------
// Main: block = 64 tokens x 128 d x 16 slots (kb quarter). 4 waves = d-quarters.
// Phase 1: stage x tile bf16 in LDS in A-FRAG order (lane-contiguous b128 reads).
// Phase 2: attn via MFMA + softmax -> fp32 LDS (only this block's 16 slots).
// Phase 3: A-frags held in REGISTERS for all slots; B double-buffered in regs
//          (prefetch slot ml+1 during ml's 32 MFMAs); scale S into C per slot.
// Epilogue: atomicAdd into zeroed out (4 kb partials).
// ---------------------------------------------------------------------------
__global__ __launch_bounds__(256, 2) void main_kernel(
    const float* __restrict__ x, const float* __restrict__ cb,
    const ushort_t* __restrict__ kp_sw, const uint4v* __restrict__ ops_sw,
    float* __restrict__ out)
{
    __shared__ ushort_t xs[8192];        // [tg4][ki4][lane64][8] bf16 = 16 KB
    __shared__ float attn_f[16 * AP];    // [m_local 16][t 64+pad] fp32

    const int tid = threadIdx.x;
    const int lane = tid & 63;
    const int w = tid >> 6;              // wave id = d-quarter (wx)
    const int q = lane >> 4;
    const int l15 = lane & 15;
    const int tb = blockIdx.x >> 2;
    const int kb = blockIdx.x & 3;
    const int t0 = tb * 64;

    // ---- Phase 1: stage x tile (64 x 128) -> bf16 frag order
    {
        const float4* x4 = (const float4*)(x + (size_t)t0 * 128);
        #pragma unroll
        for (int it = 0; it < 4; ++it) {
            int i = it * 256 + tid;              // [0,1024): (t, k-octet)
            int t = i >> 4, kc = i & 15;
            float4 a = x4[t * 32 + kc * 2];
            float4 b = x4[t * 32 + kc * 2 + 1];
            int tg = t >> 4, ki = kc >> 2, lp = (kc & 3) * 16 + (t & 15);
            uint4v o = { pack2(a.x, a.y), pack2(a.z, a.w),
                         pack2(b.x, b.y), pack2(b.z, b.w) };
            *(uint4v*)&xs[((tg * 4 + ki) * 64 + lp) << 3] = o;
        }
    }
    __syncthreads();

    // ---- Phase 2: attn for tokens w*16..w*16+15; keep only kb's 16 slots (fp32)
    {
        f32x4 L0 = {0,0,0,0}, L1 = {0,0,0,0}, L2 = {0,0,0,0}, L3 = {0,0,0,0};
        const uint4v* kpf = (const uint4v*)kp_sw;
        #pragma unroll
        for (int ki = 0; ki < 4; ++ki) {
            bf16x8 a = *(const bf16x8*)&xs[((w * 4 + ki) * 64 + lane) << 3];
            L0 = __builtin_amdgcn_mfma_f32_16x16x32_bf16(a, as_bf(kpf[(ki*4+0)*64 + lane]), L0, 0,0,0);
            L1 = __builtin_amdgcn_mfma_f32_16x16x32_bf16(a, as_bf(kpf[(ki*4+1)*64 + lane]), L1, 0,0,0);
            L2 = __builtin_amdgcn_mfma_f32_16x16x32_bf16(a, as_bf(kpf[(ki*4+2)*64 + lane]), L2, 0,0,0);
            L3 = __builtin_amdgcn_mfma_f32_16x16x32_bf16(a, as_bf(kpf[(ki*4+3)*64 + lane]), L3, 0,0,0);
        }
        float c0 = cb[l15], c1 = cb[16 + l15], c2 = cb[32 + l15], c3 = cb[48 + l15];
        #pragma unroll
        for (int r = 0; r < 4; ++r) {
            float v0 = (L0[r] + c0) * RS;
            float v1 = (L1[r] + c1) * RS;
            float v2 = (L2[r] + c2) * RS;
            float v3 = (L3[r] + c3) * RS;
            float mx = fmaxf(fmaxf(v0, v1), fmaxf(v2, v3));
            #pragma unroll
            for (int off = 1; off < 16; off <<= 1) mx = fmaxf(mx, __shfl_xor(mx, off));
            float e0 = __expf(v0 - mx), e1 = __expf(v1 - mx),
                  e2 = __expf(v2 - mx), e3 = __expf(v3 - mx);
            float sm = e0 + e1 + e2 + e3;
            #pragma unroll
            for (int off = 1; off < 16; off <<= 1) sm += __shfl_xor(sm, off);
            float inv = 1.0f / sm;
            float es = (kb == 0) ? e0 : (kb == 1) ? e1 : (kb == 2) ? e2 : e3;
            attn_f[l15 * AP + w * 16 + q * 4 + r] = es * inv;
        }
    }

    // ---- A-frags for ALL 64 tokens, held in registers for the whole K-loop
    bf16x8 A[4][4];
    #pragma unroll
    for (int tf = 0; tf < 4; ++tf)
        #pragma unroll
        for (int ki = 0; ki < 4; ++ki)
            A[tf][ki] = *(const bf16x8*)&xs[((tf * 4 + ki) * 64 + lane) << 3];

    __syncthreads();

    // ---- Phase 3: 16 slots, B double-buffered in registers
    const uint4v* ob = ops_sw + (size_t)(kb * 16) * 2048 + (w * 2) * 64 + lane;
    f32x4 C[4][2] = {};
    uint4v B[2][8];
    #pragma unroll
    for (int ki = 0; ki < 4; ++ki)
        #pragma unroll
        for (int df = 0; df < 2; ++df)
            B[0][ki * 2 + df] = ob[ki * 512 + df * 64];

    #pragma unroll 2
    for (int ml = 0; ml < 16; ++ml) {
        const int cur = ml & 1, nxt = cur ^ 1;
        const size_t mb = (size_t)((ml < 15) ? ml + 1 : 0) * 2048;  // clamp: no OOB
        #pragma unroll
        for (int ki = 0; ki < 4; ++ki)
            #pragma unroll
            for (int df = 0; df < 2; ++df)
                B[nxt][ki * 2 + df] = ob[mb + ki * 512 + df * 64];

        f32x4 S[4][2] = {};
        #pragma unroll
        for (int ki = 0; ki < 4; ++ki)
            #pragma unroll
            for (int df = 0; df < 2; ++df) {
                bf16x8 b = as_bf(B[cur][ki * 2 + df]);
                #pragma unroll
                for (int tf = 0; tf < 4; ++tf)
                    S[tf][df] = __builtin_amdgcn_mfma_f32_16x16x32_bf16(A[tf][ki], b, S[tf][df], 0,0,0);
            }

        #pragma unroll
        for (int tf = 0; tf < 4; ++tf) {
            f32x4 af = *(const f32x4*)&attn_f[ml * AP + tf * 16 + q * 4];
            #pragma unroll
            for (int df = 0; df < 2; ++df)
                #pragma unroll
                for (int r = 0; r < 4; ++r)
                    C[tf][df][r] = fmaf(af[r], S[tf][df][r], C[tf][df][r]);
        }
    }

    // ---- Epilogue: 4 kb-partials summed via atomics into zeroed out
    #pragma unroll
    for (int tf = 0; tf < 4; ++tf)
        #pragma unroll
        for (int df = 0; df < 2; ++df)
            #pragma unroll
            for (int r = 0; r < 4; ++r) {
                int t = t0 + tf * 16 + q * 4 + r;
                int d = w * 32 + df * 16 + l15;
                atomicAdd(&out[(size_t)t * 128 + d], C[tf][df][r]);
            }
}

// ---------------------------------------------------------------------------
extern "C" void kernel_launch(void* const* d_in, const int* in_sizes, int n_in,
                              void* d_out, int out_size, void* d_ws, size_t ws_size,
                              hipStream_t stream)
{
    const float* x    = (const float*)d_in[0];   // (4,4096,128)
    const float* keys = (const float*)d_in[1];   // (64,128)
    const float* ops  = (const float*)d_in[2];   // (64,128,128)
    const float* Wq   = (const float*)d_in[3];   // (128,128)
    const float* bq   = (const float*)d_in[4];   // (128,)
    float* out = (float*)d_out;

    char* ws = (char*)d_ws;
    uint4v*   ops_sw = (uint4v*)ws;                        // 2 MB
    ushort_t* kp_sw  = (ushort_t*)(ws + 2097152);          // 16 KB
    float*    cb     = (float*)(ws + 2097152 + 16384);     // 256 B

    hipMemsetAsync(d_out, 0, (size_t)out_size * sizeof(float), stream);
    p1_kernel<<<512, 256, 0, stream>>>(ops, ops_sw);
    k0_kernel<<<64, 192, 0, stream>>>(keys, Wq, bq, kp_sw, cb);
    main_kernel<<<1024, 256, 0, stream>>>(x, cb, kp_sw, ops_sw, out);
}